// Round 12
// baseline (1337.901 us; speedup 1.0000x reference)
//
#include <hip/hip_runtime.h>
#include <stdint.h>

typedef unsigned long long u64;
typedef unsigned int u32;

#define NVERT 300000
#define NTET  1200000
#define NE    (NTET*6)              // 7,200,000 edges
#define TILE  4096
#define NTILES ((NE + TILE - 1)/TILE)   // 1758
#define IDXBITS 23
#define IDXMASK ((1u<<IDXBITS)-1)
#define CODESHIFT 24                // key = code<<24 | cross<<23 | idx ; code = e0<<19 | e1
#define RBITS 10
#define RBINS 1024
#define SORT_BASE 24
#define NPASS 4

// mapping-scatter buckets
#define BSHIFT 16
#define BSZ    65536
#define NBUCK  110
#define BPB    8
#define STAGECAP 2240

// output layout (float32 elements)
#define VERTS_OFF 0
#define FACES_OFF 21600000
#define NUMT_OFF  28800000
#define CROSS_OFF 30000000
#define CODES_ELEM 14000000         // codes at bytes 56MB..86.4MB of d_out

__constant__ int c_ea[6] = {0,0,0,1,1,2};
__constant__ int c_eb[6] = {1,2,3,2,3,3};
__constant__ int c_numtri[16] = {0,1,1,2,1,2,2,1,1,2,2,1,2,1,1,0};
__constant__ int c_tritab[16][6] = {
 {-1,-1,-1,-1,-1,-1},{1,0,2,-1,-1,-1},{4,0,3,-1,-1,-1},{1,4,2,1,3,4},
 {3,1,5,-1,-1,-1},{2,3,0,2,5,3},{1,4,0,1,5,4},{4,2,5,-1,-1,-1},
 {4,5,2,-1,-1,-1},{4,1,0,4,5,1},{3,2,0,3,5,2},{1,3,5,-1,-1,-1},
 {4,1,2,4,3,1},{3,0,4,-1,-1,-1},{2,0,1,-1,-1,-1},{-1,-1,-1,-1,-1,-1}};

__device__ __forceinline__ int sw(int j){ return j ^ ((j >> 4) & 15); }

// one thread per TET: 6 keys (packed code, cross bit) + occ nibble + fused global hists
__global__ void k_pack(const int* __restrict__ tet, const float* __restrict__ sdf,
                       u64* __restrict__ dst, float* __restrict__ occF, u32* __restrict__ hist4g){
  __shared__ u32 h4[NPASS*RBINS];   // 16KB
  int tid = threadIdx.x;
  for (int r=tid; r<NPASS*RBINS; r+=256) h4[r]=0;
  __syncthreads();
  int t = blockIdx.x*blockDim.x + tid;
  if (t < NTET){
    int4 q = ((const int4*)tet)[t];
    int v[4] = {q.x, q.y, q.z, q.w};
    u32 o[4];
    int occ = 0;
    #pragma unroll
    for (int j=0;j<4;j++){ o[j] = sdf[v[j]] > 0.f ? 1u : 0u; occ |= (int)o[j] << j; }
    occF[t] = (float)occ;
    u64 base = (u64)t*6;
    #pragma unroll
    for (int k=0;k<6;k++){
      int a = v[c_ea[k]], b = v[c_eb[k]];
      u64 cross = (o[c_ea[k]] != o[c_eb[k]]) ? 1ull : 0ull;
      int e0 = min(a,b), e1 = max(a,b);
      u64 code = ((u64)e0 << 19) | (u64)e1;     // lexicographic == e0*NVERT+e1 order
      u64 key = (code << CODESHIFT) | (cross << IDXBITS) | (base + (u64)k);
      dst[base+k] = key;
      #pragma unroll
      for (int p=0;p<NPASS;p++)
        atomicAdd(&h4[p*RBINS + (u32)((key >> (SORT_BASE + RBITS*p)) & (RBINS-1))], 1u);
    }
  }
  __syncthreads();
  for (int r=tid; r<NPASS*RBINS; r+=256){
    u32 c = h4[r];
    if (c) atomicAdd(&hist4g[r], c);
  }
}

__global__ void k_psd(const float* __restrict__ pos, const float* __restrict__ sdf,
                      float4* __restrict__ psd){
  int v = blockIdx.x*blockDim.x + threadIdx.x;
  if (v < NVERT) psd[v] = make_float4(pos[3*v], pos[3*v+1], pos[3*v+2], sdf[v]);
}

__global__ void k_fillm1(float4* __restrict__ p, int n4){
  int i = blockIdx.x*blockDim.x + threadIdx.x;
  if (i < n4) p[i] = make_float4(-1.f,-1.f,-1.f,-1.f);
}

// exclusive scan of each pass's global histogram; grid = NPASS, block = 1024
__global__ __launch_bounds__(1024) void k_scan4(const u32* __restrict__ hist4g, u32* __restrict__ digitOff4){
  __shared__ u32 s[RBINS];
  int tid = threadIdx.x;
  const u32* src = hist4g + (size_t)blockIdx.x * RBINS;
  u32* dst = digitOff4 + (size_t)blockIdx.x * RBINS;
  u32 x = src[tid];
  s[tid]=x; __syncthreads();
  for (int off=1; off<RBINS; off<<=1){
    u32 t=(tid>=off)?s[tid-off]:0;
    __syncthreads();
    s[tid]+=t;
    __syncthreads();
  }
  dst[tid] = s[tid]-x;
}

// onesweep scatter: ticket-ordered tiles, in-kernel hist, 3-round 4/4/2-bit splits,
// W=16 batched decoupled lookback
__global__ __launch_bounds__(256) void k_scatter_os(const u64* __restrict__ src, u64* __restrict__ dst,
      const u32* __restrict__ digitOff, u32* __restrict__ pst, u32* __restrict__ ticket, int shift){
  __shared__ u64 keys[TILE];
  __shared__ u32 cnt[RBINS];
  __shared__ unsigned short lstart[RBINS];
  __shared__ u64 wsum4[4][4];
  __shared__ int stile;
  int tid = threadIdx.x;
  if (tid==0) stile = (int)atomicAdd(ticket, 1u);
  for (int r=tid;r<RBINS;r+=256) cnt[r]=0;
  __syncthreads();
  int tile = stile;
  int base = tile * TILE;
  // vectorized per-thread-contiguous load (LDS content identical via sw)
  int lbase = tid*16;
  int gi = base + lbase;
  u64 kk[16];
  if (gi + 16 <= NE){
    const ulonglong2* p2 = (const ulonglong2*)(src + gi);
    #pragma unroll
    for (int k2=0;k2<8;k2++){ ulonglong2 t = p2[k2]; kk[2*k2]=t.x; kk[2*k2+1]=t.y; }
  } else {
    #pragma unroll
    for (int k=0;k<16;k++) kk[k] = (gi+k < NE) ? src[gi+k] : ~0ull;
  }
  #pragma unroll
  for (int k=0;k<16;k++){
    keys[sw(lbase+k)] = kk[k];
    if (gi+k < NE) atomicAdd(&cnt[(u32)((kk[k] >> shift) & (RBINS-1))], 1u);
  }
  __syncthreads();
  // publish PARTIAL counts early (unblocks successors)
  u32 oc[4];
  #pragma unroll
  for (int r=0;r<4;r++){
    int d = tid + r*256;
    oc[r] = cnt[d];
    __hip_atomic_store(&pst[(size_t)tile*RBINS + d], oc[r] | 0x40000000u,
                       __ATOMIC_RELAXED, __HIP_MEMORY_SCOPE_AGENT);
  }
  // 3 rounds of stable splits: 4 bits, 4 bits, 2 bits (LSB->MSB within digit)
  const int   rsh[3]  = {shift, shift+4, shift+8};
  const u32   rmsk[3] = {15u, 15u, 3u};
  int mywave = tid >> 6;
  for (int rr=0; rr<3; rr++){
    int sh = rsh[rr];
    u32 msk = rmsk[rr];
    u64 myk[16];
    u64 c[4] = {0,0,0,0};
    u32 vp0 = 0, vp1 = 0;                // 16 elems x 4-bit digits
    #pragma unroll
    for (int k=0;k<16;k++){
      myk[k] = keys[sw(tid*16+k)];
      u32 d4 = (u32)((myk[k] >> sh) & msk);
      if (k < 8) vp0 |= d4 << (4*k); else vp1 |= d4 << (4*(k-8));
      c[d4>>2] += 1ull << (16*(d4&3));
    }
    // wave64 inclusive scan of 4 packed u64 counters
    u64 v0=c[0], v1=c[1], v2=c[2], v3=c[3];
    #pragma unroll
    for (int off=1; off<64; off<<=1){
      u64 t0=__shfl_up(v0,off,64), t1=__shfl_up(v1,off,64);
      u64 t2=__shfl_up(v2,off,64), t3=__shfl_up(v3,off,64);
      if ((tid & 63) >= off){ v0+=t0; v1+=t1; v2+=t2; v3+=t3; }
    }
    if ((tid & 63) == 63){
      wsum4[mywave][0]=v0; wsum4[mywave][1]=v1; wsum4[mywave][2]=v2; wsum4[mywave][3]=v3;
    }
    __syncthreads();
    u64 pre[4]={0,0,0,0}, tot[4]={0,0,0,0};
    #pragma unroll
    for (int wv=0; wv<4; wv++){
      #pragma unroll
      for (int q=0;q<4;q++){
        u64 x = wsum4[wv][q];
        if (wv < mywave) pre[q] += x;
        tot[q] += x;
      }
    }
    u64 run[4];
    run[0]=v0+pre[0]-c[0]; run[1]=v1+pre[1]-c[1]; run[2]=v2+pre[2]-c[2]; run[3]=v3+pre[3]-c[3];
    // exclusive bin-prefix packed into Bp[4] (aligned with run fields)
    u64 Bp[4] = {0,0,0,0};
    u32 acc = 0;
    #pragma unroll
    for (int b=0;b<16;b++){
      Bp[b>>2] |= (u64)acc << (16*(b&3));
      acc += (u32)((tot[b>>2] >> (16*(b&3))) & 0xFFFF);
    }
    #pragma unroll
    for (int k=0;k<16;k++){
      u32 d4 = (k<8) ? ((vp0 >> (4*k)) & 15u) : ((vp1 >> (4*(k-8))) & 15u);
      u32 q = d4>>2, s2 = d4&3;
      u32 pos = (u32)((Bp[q]>>(16*s2)) & 0xFFFF) + (u32)((run[q]>>(16*s2)) & 0xFFFF);
      run[q] += 1ull << (16*s2);
      keys[sw((int)pos)] = myk[k];
    }
    __syncthreads();
  }
  // local run starts
  for (int k=0;k<16;k++){
    int j = k*256+tid;
    u32 d = (u32)((keys[sw(j)] >> shift) & (RBINS-1));
    bool headj = (j==0) || (((keys[sw(j-1)] >> shift) & (RBINS-1)) != d);
    if (headj) lstart[d] = (unsigned short)j;
  }
  // W=16 batched lookback per digit (addresses independent; early exit on DONE)
  u32 sum4[4];
  #pragma unroll 1
  for (int r=0;r<4;r++){
    int d = tid + r*256;
    u32 sum = 0;
    int t2 = tile-1;
    while (t2 >= 0){
      int W = (t2+1 < 16) ? (t2+1) : 16;
      u32 vv[16];
      #pragma unroll
      for (int w2=0; w2<16; w2++){
        vv[w2] = (w2<W) ? __hip_atomic_load(&pst[(size_t)(t2-w2)*RBINS + d],
                              __ATOMIC_RELAXED, __HIP_MEMORY_SCOPE_AGENT) : 0u;
      }
      int w2=0; bool done=false;
      for (; w2<W; ++w2){
        u32 x = vv[w2];
        if (!(x & 0xC0000000u)) break;        // unpublished — retry from here
        sum += x & 0x0FFFFFFFu;
        if (x & 0x80000000u){ done=true; break; }
      }
      if (done) break;
      if (w2==0) __builtin_amdgcn_s_sleep(1);
      t2 -= w2;
    }
    sum4[r] = sum;
  }
  #pragma unroll
  for (int r=0;r<4;r++){
    int d = tid + r*256;
    __hip_atomic_store(&pst[(size_t)tile*RBINS + d], (oc[r] + sum4[r]) | 0x80000000u,
                       __ATOMIC_RELAXED, __HIP_MEMORY_SCOPE_AGENT);
    cnt[d] = sum4[r];
  }
  __syncthreads();
  for (int k=0;k<16;k++){
    int j = k*256+tid;
    u64 key = keys[sw(j)];
    if (key == ~0ull) continue;
    u32 d = (u32)((key >> shift) & (RBINS-1));
    u32 gpos = digitOff[d] + cnt[d] + (u32)j - (u32)lstart[d];
    dst[gpos] = key;
  }
}

// streaming per-tile (head, crossHead) counts — vectorized loads
__global__ __launch_bounds__(256) void k_tilesum(const u64* __restrict__ A, u64* __restrict__ tileSums){
  __shared__ u64 s[256];
  int tid = threadIdx.x;
  int start = blockIdx.x*TILE + tid*16;
  u64 myk[16];
  if (start < NE){
    const ulonglong2* A2 = (const ulonglong2*)(A + start);
    #pragma unroll
    for (int k2=0;k2<8;k2++){ ulonglong2 t = A2[k2]; myk[2*k2]=t.x; myk[2*k2+1]=t.y; }
  } else {
    #pragma unroll
    for (int k=0;k<16;k++) myk[k]=0;
  }
  u64 prev = (start > 0 && start <= NE) ? A[start-1] : ~0ull;
  u32 th=0, tc=0;
  #pragma unroll
  for (int k=0;k<16;k++){
    int i = start + k;
    if (i < NE){
      u64 v = myk[k];
      if ((v>>CODESHIFT) != (prev>>CODESHIFT)){
        th++;
        if ((v>>IDXBITS) & 1ull) tc++;
      }
      prev = v;
    }
  }
  s[tid] = ((u64)th<<32) | (u64)tc;
  __syncthreads();
  for (int off=128; off>0; off>>=1){
    if (tid<off) s[tid]+=s[tid+off];
    __syncthreads();
  }
  if (tid==0) tileSums[blockIdx.x] = s[0];
}

// exclusive scan over tiles; tileOff[NTILES] = grand total
__global__ void k_scan_tiles(u64* __restrict__ tileSums, u64* __restrict__ tileOff){
  __shared__ u64 s[256];
  int tid = threadIdx.x;
  u64 carry=0;
  for (int start=0; start<NTILES; start+=256){
    int idx=start+tid;
    u64 x = (idx<NTILES)? tileSums[idx] : 0;
    s[tid]=x; __syncthreads();
    for (int off=1;off<256;off<<=1){
      u64 t=(tid>=off)?s[tid-off]:0;
      __syncthreads();
      s[tid]+=t;
      __syncthreads();
    }
    u64 incl=s[tid], tot=s[255];
    if (idx<NTILES) tileOff[idx] = carry + incl - x;
    carry += tot;
    __syncthreads();
  }
  if (tid==0) tileOff[NTILES] = carry;
}

// streaming pass: crossing flags + staged pairs + dense codes[m]. NO gathers.
__global__ __launch_bounds__(256) void k_emit_light(const u64* __restrict__ A,
     const u64* __restrict__ tileOff, u64* __restrict__ pairs, u32* __restrict__ cursors,
     u64* __restrict__ codes, float* __restrict__ crossing_out){
  __shared__ u64 s[256];
  __shared__ u32 cnt[NBUCK], lcur[NBUCK];
  __shared__ u32 lofs[NBUCK+1];
  __shared__ u32 gbase[NBUCK];
  __shared__ u32 pscan[128];
  __shared__ u64 stage[STAGECAP];
  int tid=threadIdx.x, blk=blockIdx.x;
  int start = blk*TILE + tid*16;
  if (tid < NBUCK){ cnt[tid]=0; lcur[tid]=0; }
  u64 myk[16];
  if (start < NE){
    const ulonglong2* A2 = (const ulonglong2*)(A + start);
    #pragma unroll
    for (int k2=0;k2<8;k2++){ ulonglong2 t = A2[k2]; myk[2*k2]=t.x; myk[2*k2+1]=t.y; }
  } else {
    #pragma unroll
    for (int k=0;k<16;k++) myk[k]=0;
  }
  u64 prev = (start > 0 && start <= NE) ? A[start-1] : ~0ull;
  u32 headm=0, crossm=0;
  #pragma unroll
  for (int k=0;k<16;k++){
    int i = start + k;
    if (i<NE){
      u64 v = myk[k];
      if ((v>>CODESHIFT) != (prev>>CODESHIFT)) headm |= 1u<<k;
      if ((v>>IDXBITS) & 1ull) crossm |= 1u<<k;
      prev = v;
    }
  }
  __syncthreads();
  #pragma unroll
  for (int k=0;k<16;k++){
    if ((start+k) < NE && ((crossm>>k)&1u))
      atomicAdd(&cnt[((u32)myk[k] & IDXMASK)>>BSHIFT], 1u);
  }
  u32 th = __popc(headm), tc = __popc(headm & crossm);
  u64 x = ((u64)th<<32)|(u64)tc;
  s[tid]=x; __syncthreads();
  for (int off=1;off<256;off<<=1){
    u64 t=(tid>=off)?s[tid-off]:0;
    __syncthreads();
    s[tid]+=t;
    __syncthreads();
  }
  u64 excl = s[tid]-x;
  if (tid < 128) pscan[tid] = (tid < NBUCK) ? cnt[tid] : 0;
  __syncthreads();
  for (int off=1; off<128; off<<=1){
    u32 t = 0;
    if (tid < 128 && tid >= off) t = pscan[tid-off];
    __syncthreads();
    if (tid < 128) pscan[tid] += t;
    __syncthreads();
  }
  if (tid < NBUCK) lofs[tid] = pscan[tid] - cnt[tid];
  if (tid == 0) lofs[NBUCK] = pscan[127];
  if (tid < NBUCK) gbase[tid] = atomicAdd(&cursors[tid], cnt[tid]);
  __syncthreads();
  bool use_stage = (lofs[NBUCK] <= STAGECAP);
  u64 baseOff = tileOff[blk] + excl;
  u32 H = (u32)(baseOff>>32);
  u32 C = (u32)(baseOff & 0xFFFFFFFFull);
  #pragma unroll
  for (int k=0;k<16;k++){
    int i = start+k;
    if (i>=NE) break;
    bool head  = (headm>>k)&1u;
    bool cross = (crossm>>k)&1u;
    if (head){ H++; if(cross) C++; }
    if (cross){
      int m = (int)C-1;
      u32 orig = (u32)myk[k] & IDXMASK;
      u32 b = orig>>BSHIFT;
      u32 r = atomicAdd(&lcur[b], 1u);
      u64 pr = ((u64)orig<<32) | (u64)(u32)m;
      if (use_stage) stage[lofs[b] + r] = pr;
      else           pairs[(size_t)b*BSZ + gbase[b] + r] = pr;
    }
    if (head){
      crossing_out[H-1] = cross ? 1.f : 0.f;
      if (cross) codes[C-1] = myk[k]>>CODESHIFT;
    }
  }
  __syncthreads();
  if (use_stage){
    int ncross = (int)lofs[NBUCK];
    for (int j = tid; j < ncross; j += 256){
      int lo=0, hi=NBUCK;
      while (hi - lo > 1){ int mid=(lo+hi)>>1; if ((int)lofs[mid] <= j) lo=mid; else hi=mid; }
      pairs[(size_t)lo*BSZ + gbase[lo] + (u32)(j - (int)lofs[lo])] = stage[j];
    }
  }
}

// gather-only verts pass; 40KB dummy LDS caps occupancy so psd stays L2-resident
__global__ __launch_bounds__(256) void k_verts(const u64* __restrict__ codes,
     const float4* __restrict__ psd, const u64* __restrict__ totptr, float* __restrict__ verts){
  __shared__ u64 dummy[5120];
  u32 ncross = (u32)(totptr[0] & 0xFFFFFFFFull);
  u32 stride = gridDim.x * blockDim.x;
  for (u32 i = blockIdx.x*blockDim.x + threadIdx.x; i < ncross; i += stride){
    u64 code = codes[i];
    u32 u0 = (u32)(code >> 19), u1 = (u32)(code & 0x7FFFFull);
    float4 a = psd[u0], b = psd[u1];
    float denom = a.w - b.w;
    float w0 = (-b.w)/denom, w1 = a.w/denom;
    verts[3*i+0] = a.x*w0 + b.x*w1;
    verts[3*i+1] = a.y*w0 + b.y*w1;
    verts[3*i+2] = a.z*w0 + b.z*w1;
  }
  if ((int)ncross < -1){ dummy[threadIdx.x] = codes[0]; verts[0] = (float)dummy[255]; }
}

__global__ void k_map_scatter(const u64* __restrict__ pairs, const u32* __restrict__ cursors,
                              float* __restrict__ mapF){
  int b = blockIdx.x / BPB, sub = blockIdx.x % BPB;
  u32 n = cursors[b];
  const u64* p = pairs + (size_t)b*BSZ;
  for (u32 i = (u32)(sub*256 + threadIdx.x); i < n; i += BPB*256){
    u64 v = p[i];
    mapF[(u32)(v>>32)] = (float)(int)(u32)v;
  }
}

__global__ void k_faces(const float* __restrict__ occF, float* faceRegion, float* __restrict__ numt){
  int t = blockIdx.x*blockDim.x + threadIdx.x;
  if (t>=NTET) return;
  int occ = (int)occF[t];
  int ntri = c_numtri[occ];
  float em[6];
  #pragma unroll
  for (int j=0;j<6;j++) em[j] = faceRegion[t*6+j];
  float f[6];
  #pragma unroll
  for (int j=0;j<6;j++){
    int tri = c_tritab[occ][j];
    f[j] = ((j/3) < ntri) ? em[tri] : -1.f;
  }
  #pragma unroll
  for (int j=0;j<6;j++) faceRegion[t*6+j] = f[j];
  numt[t] = (float)ntri;
}

extern "C" void kernel_launch(void* const* d_in, const int* in_sizes, int n_in,
                              void* d_out, int out_size, void* d_ws, size_t ws_size,
                              hipStream_t stream) {
  const float* pos = (const float*)d_in[0];
  const float* sdf = (const float*)d_in[1];
  const int*   tet = (const int*)d_in[2];
  float* out = (float*)d_out;

  // ws layout
  char* w = (char*)d_ws;
  u64* bufA      = (u64*)w;                        // 57,600,000
  u32* hist4g    = (u32*)(w + 57600000);           // 16,384
  u32* digitOff4 = (u32*)(w + 57616384);           // 16,384
  u64* tileSums  = (u64*)(w + 57632768);           // 14,064
  u64* tileOff   = (u64*)(w + 57646832);           // 14,072 (NTILES+1)
  u32* cursors   = (u32*)(w + 57660904);           // 440
  u32* tickets   = (u32*)(w + 57661344);           // 16 -> pad to 57661952
  float4* psd    = (float4*)(w + 57661952);        // 4,800,000
  u32* pst       = (u32*)(w + 62461952);           // 4*1758*1024*4 = 28,835,840 (sort-time)
  u64* pairs_ws  = (u64*)(w + 62461952);           // 57,600,000 (emit-time, aliases pst)

  u64* bufB  = (u64*)d_out;                        // sort pong buffer (bytes 0..57.6MB)
  u64* codes = (u64*)(out + CODES_ELEM);           // bytes 56MB..86.4MB

  hipMemsetAsync(hist4g, 0, NPASS*RBINS*sizeof(u32), stream);
  hipMemsetAsync(tickets, 0, NPASS*sizeof(u32), stream);
  hipMemsetAsync(pst, 0, (size_t)NPASS*NTILES*RBINS*sizeof(u32), stream);

  k_pack<<<(NTET+255)/256, 256, 0, stream>>>(tet, sdf, bufA, out + NUMT_OFF, hist4g);
  k_psd<<<(NVERT+255)/256, 256, 0, stream>>>(pos, sdf, psd);
  k_fillm1<<<(7200000/4 + 255)/256, 256, 0, stream>>>((float4*)(out + FACES_OFF), 7200000/4);

  k_scan4<<<NPASS, 1024, 0, stream>>>(hist4g, digitOff4);

  u64 *src = bufA, *dst = bufB;
  for (int p=0; p<NPASS; p++){
    int shift = SORT_BASE + RBITS*p;
    k_scatter_os<<<NTILES, 256, 0, stream>>>(src, dst,
        digitOff4 + (size_t)p*RBINS, pst + (size_t)p*NTILES*RBINS, tickets + p, shift);
    u64* tmp = src; src = dst; dst = tmp;
  }
  // 4 passes: bufA->bufB->bufA->bufB->bufA — sorted array in bufA (ws)

  k_tilesum<<<NTILES, 256, 0, stream>>>(bufA, tileSums);
  k_scan_tiles<<<1, 256, 0, stream>>>(tileSums, tileOff);

  hipMemsetAsync(out + CROSS_OFF, 0, (size_t)7200000*4, stream);
  hipMemsetAsync(cursors, 0, NBUCK*sizeof(u32), stream);

  k_emit_light<<<NTILES, 256, 0, stream>>>(bufA, tileOff, pairs_ws, cursors,
                                           codes, out + CROSS_OFF);

  hipMemsetAsync(out + VERTS_OFF, 0, (size_t)CODES_ELEM*4, stream);   // verts bytes 0..56MB
  k_verts<<<1024, 256, 0, stream>>>(codes, psd, tileOff + NTILES, out + VERTS_OFF);
  hipMemsetAsync(out + CODES_ELEM, 0, (size_t)(21600000-CODES_ELEM)*4, stream); // wipe codes

  k_map_scatter<<<NBUCK*BPB, 256, 0, stream>>>(pairs_ws, cursors, out + FACES_OFF);
  k_faces<<<(NTET+255)/256, 256, 0, stream>>>(out + NUMT_OFF, out + FACES_OFF, out + NUMT_OFF);
}

// Round 13
// 633.183 us; speedup vs baseline: 2.1130x; 2.1130x over previous
//
#include <hip/hip_runtime.h>
#include <stdint.h>

typedef unsigned long long u64;
typedef unsigned int u32;

#define NVERT 300000
#define NTET  1200000
#define NE    (NTET*6)              // 7,200,000 edges
#define TILE  4096
#define NTILES ((NE + TILE - 1)/TILE)   // 1758
#define IDXBITS 23
#define IDXMASK ((1u<<IDXBITS)-1)
#define CODESHIFT 24                // key = code<<24 | cross<<23 | idx ; code = e0<<19 | e1
#define NBUCKS 4688                 // bucket = key>>49 = e0>>6 ; max bucket ~3350 << 4096
#define BUCKSHIFT 49

// mapping-scatter buckets (faces mapping)
#define BSHIFT 16
#define BSZ    65536
#define NBUCK  110
#define BPB    8
#define STAGECAP 2240

// output layout (float32 elements)
#define VERTS_OFF 0
#define FACES_OFF 21600000
#define NUMT_OFF  28800000
#define CROSS_OFF 30000000
#define CODES_ELEM 14000000         // codes at bytes 56MB..86.4MB of d_out

__constant__ int c_ea[6] = {0,0,0,1,1,2};
__constant__ int c_eb[6] = {1,2,3,2,3,3};
__constant__ int c_numtri[16] = {0,1,1,2,1,2,2,1,1,2,2,1,2,1,1,0};
__constant__ int c_tritab[16][6] = {
 {-1,-1,-1,-1,-1,-1},{1,0,2,-1,-1,-1},{4,0,3,-1,-1,-1},{1,4,2,1,3,4},
 {3,1,5,-1,-1,-1},{2,3,0,2,5,3},{1,4,0,1,5,4},{4,2,5,-1,-1,-1},
 {4,5,2,-1,-1,-1},{4,1,0,4,5,1},{3,2,0,3,5,2},{1,3,5,-1,-1,-1},
 {4,1,2,4,3,1},{3,0,4,-1,-1,-1},{2,0,1,-1,-1,-1},{-1,-1,-1,-1,-1,-1}};

__device__ __forceinline__ int sw(int j){ return j ^ ((j >> 4) & 15); }

// one thread per TET: 6 keys + occ nibble + fused global MSB-bucket histogram
__global__ void k_pack(const int* __restrict__ tet, const float* __restrict__ sdf,
                       u64* __restrict__ dst, float* __restrict__ occF, u32* __restrict__ hist){
  __shared__ u32 h[NBUCKS];   // 18.75KB
  int tid = threadIdx.x;
  for (int r=tid; r<NBUCKS; r+=256) h[r]=0;
  __syncthreads();
  int t = blockIdx.x*blockDim.x + tid;
  if (t < NTET){
    int4 q = ((const int4*)tet)[t];
    int v[4] = {q.x, q.y, q.z, q.w};
    u32 o[4];
    int occ = 0;
    #pragma unroll
    for (int j=0;j<4;j++){ o[j] = sdf[v[j]] > 0.f ? 1u : 0u; occ |= (int)o[j] << j; }
    occF[t] = (float)occ;
    u64 base = (u64)t*6;
    #pragma unroll
    for (int k=0;k<6;k++){
      int a = v[c_ea[k]], b = v[c_eb[k]];
      u64 cross = (o[c_ea[k]] != o[c_eb[k]]) ? 1ull : 0ull;
      int e0 = min(a,b), e1 = max(a,b);
      u64 code = ((u64)e0 << 19) | (u64)e1;     // lexicographic == e0*NVERT+e1 order
      u64 key = (code << CODESHIFT) | (cross << IDXBITS) | (base + (u64)k);
      dst[base+k] = key;
      atomicAdd(&h[(u32)(key >> BUCKSHIFT)], 1u);
    }
  }
  __syncthreads();
  for (int r=tid; r<NBUCKS; r+=256){
    u32 c = h[r];
    if (c) atomicAdd(&hist[r], c);
  }
}

__global__ void k_psd(const float* __restrict__ pos, const float* __restrict__ sdf,
                      float4* __restrict__ psd){
  int v = blockIdx.x*blockDim.x + threadIdx.x;
  if (v < NVERT) psd[v] = make_float4(pos[3*v], pos[3*v+1], pos[3*v+2], sdf[v]);
}

__global__ void k_fillm1(float4* __restrict__ p, int n4){
  int i = blockIdx.x*blockDim.x + threadIdx.x;
  if (i < n4) p[i] = make_float4(-1.f,-1.f,-1.f,-1.f);
}

// exclusive scan over buckets; writes bucket offsets AND initializes global cursors
__global__ __launch_bounds__(1024) void k_scan_buckets(const u32* __restrict__ hist,
     u32* __restrict__ boff, u32* __restrict__ gcur){
  __shared__ u32 s[1024];
  int tid = threadIdx.x;
  u32 carry = 0;
  for (int start=0; start<NBUCKS; start+=1024){
    int idx = start + tid;
    u32 x = (idx < NBUCKS) ? hist[idx] : 0;
    s[tid] = x; __syncthreads();
    for (int off=1; off<1024; off<<=1){
      u32 t = (tid >= off) ? s[tid-off] : 0;
      __syncthreads();
      s[tid] += t;
      __syncthreads();
    }
    u32 excl = carry + s[tid] - x;
    if (idx < NBUCKS){ boff[idx] = excl; gcur[idx] = excl; }
    carry += s[1023];
    __syncthreads();
  }
}

// pass 1: unstable MSB-bucket partition (no splits, no lookback)
__global__ __launch_bounds__(256) void k_bucket_scatter(const u64* __restrict__ src,
     u64* __restrict__ dst, u32* __restrict__ gcur){
  __shared__ u32 cnt[NBUCKS];   // 18.75KB
  __shared__ u32 cur[NBUCKS];   // 18.75KB
  int tid = threadIdx.x;
  for (int r=tid;r<NBUCKS;r+=256) cnt[r]=0;
  __syncthreads();
  int gi = blockIdx.x*TILE + tid*16;
  u64 kk[16];
  if (gi + 16 <= NE){
    const ulonglong2* p2 = (const ulonglong2*)(src + gi);
    #pragma unroll
    for (int k2=0;k2<8;k2++){ ulonglong2 t = p2[k2]; kk[2*k2]=t.x; kk[2*k2+1]=t.y; }
  } else {
    #pragma unroll
    for (int k=0;k<16;k++) kk[k] = (gi+k < NE) ? src[gi+k] : 0ull;
  }
  #pragma unroll
  for (int k=0;k<16;k++){
    if (gi+k < NE) atomicAdd(&cnt[(u32)(kk[k] >> BUCKSHIFT)], 1u);
  }
  __syncthreads();
  for (int r=tid;r<NBUCKS;r+=256){
    u32 c = cnt[r];
    cur[r] = c ? atomicAdd(&gcur[r], c) : 0u;
  }
  __syncthreads();
  #pragma unroll
  for (int k=0;k<16;k++){
    if (gi+k < NE){
      u32 b = (u32)(kk[k] >> BUCKSHIFT);
      u32 p = atomicAdd(&cur[b], 1u);
      dst[p] = kk[k];
    }
  }
}

// pass 2: full in-LDS sort of one bucket (13 rounds of 2-bit stable splits, bits 24..49)
__global__ __launch_bounds__(256) void k_sort_bucket(const u64* __restrict__ src,
     u64* __restrict__ dst, const u32* __restrict__ hist, const u32* __restrict__ boff){
  __shared__ u64 keys[TILE];
  __shared__ u64 wsum[4];
  int b = blockIdx.x, tid = threadIdx.x;
  u32 n = hist[b];
  if (n == 0) return;
  u32 base = boff[b];
  for (int k=0;k<16;k++){
    int j = k*256 + tid;
    keys[sw(j)] = (j < (int)n) ? src[base + j] : ~0ull;
  }
  __syncthreads();
  for (int q=0;q<26;q+=2){
    int sh = 24 + q;
    u64 myk[16];
    u32 vpack = 0;
    u64 c = 0;
    #pragma unroll
    for (int k=0;k<16;k++){
      myk[k] = keys[sw(tid*16+k)];
      u32 d2 = (u32)((myk[k] >> sh) & 3);
      vpack |= d2 << (2*k);
      c += 1ull << (16*d2);
    }
    u64 v = c;
    #pragma unroll
    for (int off=1; off<64; off<<=1){
      u64 t = __shfl_up(v, off, 64);
      if ((tid & 63) >= off) v += t;
    }
    if ((tid & 63) == 63) wsum[tid >> 6] = v;
    __syncthreads();
    u64 pre = 0, tot = 0;
    #pragma unroll
    for (int wv=0; wv<4; wv++){
      u64 wsv = wsum[wv];
      if (wv < (tid >> 6)) pre += wsv;
      tot += wsv;
    }
    u64 run = v + pre - c;
    u32 T0=(u32)(tot&0xFFFF), T1=(u32)((tot>>16)&0xFFFF), T2=(u32)((tot>>32)&0xFFFF);
    u64 Bp = ((u64)(T0) << 16) | ((u64)(T0+T1) << 32) | ((u64)(T0+T1+T2) << 48);
    #pragma unroll
    for (int k=0;k<16;k++){
      u32 d2 = (vpack >> (2*k)) & 3;
      u32 pos = (u32)((Bp >> (16*d2)) & 0xFFFF) + (u32)((run >> (16*d2)) & 0xFFFF);
      run += 1ull << (16*d2);
      keys[sw((int)pos)] = myk[k];
    }
    __syncthreads();
  }
  for (int k=0;k<16;k++){
    int j = k*256 + tid;
    if (j < (int)n) dst[base + j] = keys[sw(j)];
  }
}

// streaming per-tile (head, crossHead) counts — vectorized loads
__global__ __launch_bounds__(256) void k_tilesum(const u64* __restrict__ A, u64* __restrict__ tileSums){
  __shared__ u64 s[256];
  int tid = threadIdx.x;
  int start = blockIdx.x*TILE + tid*16;
  u64 myk[16];
  if (start < NE){
    const ulonglong2* A2 = (const ulonglong2*)(A + start);
    #pragma unroll
    for (int k2=0;k2<8;k2++){ ulonglong2 t = A2[k2]; myk[2*k2]=t.x; myk[2*k2+1]=t.y; }
  } else {
    #pragma unroll
    for (int k=0;k<16;k++) myk[k]=0;
  }
  u64 prev = (start > 0 && start <= NE) ? A[start-1] : ~0ull;
  u32 th=0, tc=0;
  #pragma unroll
  for (int k=0;k<16;k++){
    int i = start + k;
    if (i < NE){
      u64 v = myk[k];
      if ((v>>CODESHIFT) != (prev>>CODESHIFT)){
        th++;
        if ((v>>IDXBITS) & 1ull) tc++;
      }
      prev = v;
    }
  }
  s[tid] = ((u64)th<<32) | (u64)tc;
  __syncthreads();
  for (int off=128; off>0; off>>=1){
    if (tid<off) s[tid]+=s[tid+off];
    __syncthreads();
  }
  if (tid==0) tileSums[blockIdx.x] = s[0];
}

// exclusive scan over tiles; tileOff[NTILES] = grand total
__global__ void k_scan_tiles(u64* __restrict__ tileSums, u64* __restrict__ tileOff){
  __shared__ u64 s[256];
  int tid = threadIdx.x;
  u64 carry=0;
  for (int start=0; start<NTILES; start+=256){
    int idx=start+tid;
    u64 x = (idx<NTILES)? tileSums[idx] : 0;
    s[tid]=x; __syncthreads();
    for (int off=1;off<256;off<<=1){
      u64 t=(tid>=off)?s[tid-off]:0;
      __syncthreads();
      s[tid]+=t;
      __syncthreads();
    }
    u64 incl=s[tid], tot=s[255];
    if (idx<NTILES) tileOff[idx] = carry + incl - x;
    carry += tot;
    __syncthreads();
  }
  if (tid==0) tileOff[NTILES] = carry;
}

// streaming pass: crossing flags + staged pairs + dense codes[m]. NO gathers.
__global__ __launch_bounds__(256) void k_emit_light(const u64* __restrict__ A,
     const u64* __restrict__ tileOff, u64* __restrict__ pairs, u32* __restrict__ cursors,
     u64* __restrict__ codes, float* __restrict__ crossing_out){
  __shared__ u64 s[256];
  __shared__ u32 cnt[NBUCK], lcur[NBUCK];
  __shared__ u32 lofs[NBUCK+1];
  __shared__ u32 gbase[NBUCK];
  __shared__ u32 pscan[128];
  __shared__ u64 stage[STAGECAP];
  int tid=threadIdx.x, blk=blockIdx.x;
  int start = blk*TILE + tid*16;
  if (tid < NBUCK){ cnt[tid]=0; lcur[tid]=0; }
  u64 myk[16];
  if (start < NE){
    const ulonglong2* A2 = (const ulonglong2*)(A + start);
    #pragma unroll
    for (int k2=0;k2<8;k2++){ ulonglong2 t = A2[k2]; myk[2*k2]=t.x; myk[2*k2+1]=t.y; }
  } else {
    #pragma unroll
    for (int k=0;k<16;k++) myk[k]=0;
  }
  u64 prev = (start > 0 && start <= NE) ? A[start-1] : ~0ull;
  u32 headm=0, crossm=0;
  #pragma unroll
  for (int k=0;k<16;k++){
    int i = start + k;
    if (i<NE){
      u64 v = myk[k];
      if ((v>>CODESHIFT) != (prev>>CODESHIFT)) headm |= 1u<<k;
      if ((v>>IDXBITS) & 1ull) crossm |= 1u<<k;
      prev = v;
    }
  }
  __syncthreads();
  #pragma unroll
  for (int k=0;k<16;k++){
    if ((start+k) < NE && ((crossm>>k)&1u))
      atomicAdd(&cnt[((u32)myk[k] & IDXMASK)>>BSHIFT], 1u);
  }
  u32 th = __popc(headm), tc = __popc(headm & crossm);
  u64 x = ((u64)th<<32)|(u64)tc;
  s[tid]=x; __syncthreads();
  for (int off=1;off<256;off<<=1){
    u64 t=(tid>=off)?s[tid-off]:0;
    __syncthreads();
    s[tid]+=t;
    __syncthreads();
  }
  u64 excl = s[tid]-x;
  if (tid < 128) pscan[tid] = (tid < NBUCK) ? cnt[tid] : 0;
  __syncthreads();
  for (int off=1; off<128; off<<=1){
    u32 t = 0;
    if (tid < 128 && tid >= off) t = pscan[tid-off];
    __syncthreads();
    if (tid < 128) pscan[tid] += t;
    __syncthreads();
  }
  if (tid < NBUCK) lofs[tid] = pscan[tid] - cnt[tid];
  if (tid == 0) lofs[NBUCK] = pscan[127];
  if (tid < NBUCK) gbase[tid] = atomicAdd(&cursors[tid], cnt[tid]);
  __syncthreads();
  bool use_stage = (lofs[NBUCK] <= STAGECAP);
  u64 baseOff = tileOff[blk] + excl;
  u32 H = (u32)(baseOff>>32);
  u32 C = (u32)(baseOff & 0xFFFFFFFFull);
  #pragma unroll
  for (int k=0;k<16;k++){
    int i = start+k;
    if (i>=NE) break;
    bool head  = (headm>>k)&1u;
    bool cross = (crossm>>k)&1u;
    if (head){ H++; if(cross) C++; }
    if (cross){
      int m = (int)C-1;
      u32 orig = (u32)myk[k] & IDXMASK;
      u32 b = orig>>BSHIFT;
      u32 r = atomicAdd(&lcur[b], 1u);
      u64 pr = ((u64)orig<<32) | (u64)(u32)m;
      if (use_stage) stage[lofs[b] + r] = pr;
      else           pairs[(size_t)b*BSZ + gbase[b] + r] = pr;
    }
    if (head){
      crossing_out[H-1] = cross ? 1.f : 0.f;
      if (cross) codes[C-1] = myk[k]>>CODESHIFT;
    }
  }
  __syncthreads();
  if (use_stage){
    int ncross = (int)lofs[NBUCK];
    for (int j = tid; j < ncross; j += 256){
      int lo=0, hi=NBUCK;
      while (hi - lo > 1){ int mid=(lo+hi)>>1; if ((int)lofs[mid] <= j) lo=mid; else hi=mid; }
      pairs[(size_t)lo*BSZ + gbase[lo] + (u32)(j - (int)lofs[lo])] = stage[j];
    }
  }
}

// gather-only verts pass; 40KB dummy LDS caps occupancy so psd stays L2-resident
__global__ __launch_bounds__(256) void k_verts(const u64* __restrict__ codes,
     const float4* __restrict__ psd, const u64* __restrict__ totptr, float* __restrict__ verts){
  __shared__ u64 dummy[5120];
  u32 ncross = (u32)(totptr[0] & 0xFFFFFFFFull);
  u32 stride = gridDim.x * blockDim.x;
  for (u32 i = blockIdx.x*blockDim.x + threadIdx.x; i < ncross; i += stride){
    u64 code = codes[i];
    u32 u0 = (u32)(code >> 19), u1 = (u32)(code & 0x7FFFFull);
    float4 a = psd[u0], b = psd[u1];
    float denom = a.w - b.w;
    float w0 = (-b.w)/denom, w1 = a.w/denom;
    verts[3*i+0] = a.x*w0 + b.x*w1;
    verts[3*i+1] = a.y*w0 + b.y*w1;
    verts[3*i+2] = a.z*w0 + b.z*w1;
  }
  if ((int)ncross < -1){ dummy[threadIdx.x] = codes[0]; verts[0] = (float)dummy[255]; }
}

__global__ void k_map_scatter(const u64* __restrict__ pairs, const u32* __restrict__ cursors,
                              float* __restrict__ mapF){
  int b = blockIdx.x / BPB, sub = blockIdx.x % BPB;
  u32 n = cursors[b];
  const u64* p = pairs + (size_t)b*BSZ;
  for (u32 i = (u32)(sub*256 + threadIdx.x); i < n; i += BPB*256){
    u64 v = p[i];
    mapF[(u32)(v>>32)] = (float)(int)(u32)v;
  }
}

__global__ void k_faces(const float* __restrict__ occF, float* faceRegion, float* __restrict__ numt){
  int t = blockIdx.x*blockDim.x + threadIdx.x;
  if (t>=NTET) return;
  int occ = (int)occF[t];
  int ntri = c_numtri[occ];
  float em[6];
  #pragma unroll
  for (int j=0;j<6;j++) em[j] = faceRegion[t*6+j];
  float f[6];
  #pragma unroll
  for (int j=0;j<6;j++){
    int tri = c_tritab[occ][j];
    f[j] = ((j/3) < ntri) ? em[tri] : -1.f;
  }
  #pragma unroll
  for (int j=0;j<6;j++) faceRegion[t*6+j] = f[j];
  numt[t] = (float)ntri;
}

extern "C" void kernel_launch(void* const* d_in, const int* in_sizes, int n_in,
                              void* d_out, int out_size, void* d_ws, size_t ws_size,
                              hipStream_t stream) {
  const float* pos = (const float*)d_in[0];
  const float* sdf = (const float*)d_in[1];
  const int*   tet = (const int*)d_in[2];
  float* out = (float*)d_out;

  // ws layout
  char* w = (char*)d_ws;
  u64* bufA     = (u64*)w;                        // 57,600,000
  u32* hist     = (u32*)(w + 57600000);           // 18,752
  u32* boff     = (u32*)(w + 57618752);           // 18,752
  u32* gcur     = (u32*)(w + 57637504);           // 18,752
  u64* tileSums = (u64*)(w + 57656256);           // 14,064
  u64* tileOff  = (u64*)(w + 57670320);           // 14,072 (NTILES+1)
  u32* cursors  = (u32*)(w + 57684392);           // 440 -> pad to 57684992
  float4* psd   = (float4*)(w + 57684992);        // 4,800,000
  u64* pairs_ws = (u64*)(w + 62484992);           // 57,600,000 -> ends 120,084,992

  u64* bufB  = (u64*)d_out;                       // bucketed keys (bytes 0..57.6MB of d_out)
  u64* codes = (u64*)(out + CODES_ELEM);          // bytes 56MB..86.4MB (after bufB dead)

  hipMemsetAsync(hist, 0, NBUCKS*sizeof(u32), stream);

  k_pack<<<(NTET+255)/256, 256, 0, stream>>>(tet, sdf, bufA, out + NUMT_OFF, hist);
  k_psd<<<(NVERT+255)/256, 256, 0, stream>>>(pos, sdf, psd);
  k_fillm1<<<(7200000/4 + 255)/256, 256, 0, stream>>>((float4*)(out + FACES_OFF), 7200000/4);

  k_scan_buckets<<<1, 1024, 0, stream>>>(hist, boff, gcur);

  // pass 1: MSB-bucket partition bufA -> bufB (unstable, no splits)
  k_bucket_scatter<<<NTILES, 256, 0, stream>>>(bufA, bufB, gcur);
  // pass 2: in-LDS sort of each bucket, bufB -> bufA (coalesced output)
  k_sort_bucket<<<NBUCKS, 256, 0, stream>>>(bufB, bufA, hist, boff);

  k_tilesum<<<NTILES, 256, 0, stream>>>(bufA, tileSums);
  k_scan_tiles<<<1, 256, 0, stream>>>(tileSums, tileOff);

  hipMemsetAsync(out + CROSS_OFF, 0, (size_t)7200000*4, stream);
  hipMemsetAsync(cursors, 0, NBUCK*sizeof(u32), stream);

  k_emit_light<<<NTILES, 256, 0, stream>>>(bufA, tileOff, pairs_ws, cursors,
                                           codes, out + CROSS_OFF);

  hipMemsetAsync(out + VERTS_OFF, 0, (size_t)CODES_ELEM*4, stream);   // verts bytes 0..56MB
  k_verts<<<1024, 256, 0, stream>>>(codes, psd, tileOff + NTILES, out + VERTS_OFF);
  hipMemsetAsync(out + CODES_ELEM, 0, (size_t)(21600000-CODES_ELEM)*4, stream); // wipe codes

  k_map_scatter<<<NBUCK*BPB, 256, 0, stream>>>(pairs_ws, cursors, out + FACES_OFF);
  k_faces<<<(NTET+255)/256, 256, 0, stream>>>(out + NUMT_OFF, out + FACES_OFF, out + NUMT_OFF);
}